// Round 4
// baseline (45.154 us; speedup 1.0000x reference)
//
#include <hip/hip_runtime.h>

// ToRMS fused: sliding RMS energy, frame=2048, hop=512, pad=1024 each side.
// y: (64, 960000) f32  ->  out: (64, 1876) f32
//
// frame sum = sum of 4 consecutive 512-sample chunk sums (2048/512 == 4).
// Single fused kernel: each block owns TBLK=157 output frames of one row,
// computes the <=160 chunk sums it needs into LDS (3-chunk halo, 1.9%
// redundant fetch), then 4-tap sum + sqrt from LDS.
// SEGS=12 -> grid = 64*12 = 768 = exactly 3 blocks/CU on 256 CUs (balanced).

#define FRAME   2048
#define HOP     512
#define NROWS   64
#define NCOLS   960000
#define CHUNKS  1875          // NCOLS / HOP (chunks never cross a row)
#define TOUT    1876          // (NCOLS + 2*1024 - FRAME)/HOP + 1
#define TBLK    157           // output frames per block
#define SEGS    12            // ceil(TOUT / TBLK): 12*157 = 1884 >= 1876
#define CMAX    (TBLK + 3)    // max chunks a block needs

typedef float f32x4 __attribute__((ext_vector_type(4)));  // native vector type:
// __builtin_nontemporal_load requires scalar/native-vector pointee.

__global__ __launch_bounds__(256) void rms_fused(const float* __restrict__ y,
                                                 float* __restrict__ out) {
    __shared__ float Ssm[CMAX];

    const int row = blockIdx.x / SEGS;
    const int seg = blockIdx.x - row * SEGS;
    const int t0  = seg * TBLK;
    const int t1  = (t0 + TBLK < TOUT) ? (t0 + TBLK) : TOUT;
    const int cLo = t0 - 2;               // first chunk index needed (may be <0)
    const int nch = (t1 + 1) - cLo + 1;   // chunks [cLo, t1+1] inclusive

    const int lane = threadIdx.x & 63;
    const int wave = threadIdx.x >> 6;    // 4 waves per block

    const float* yrow = y + (size_t)row * NCOLS;

    // Phase 1: each wave computes chunk sums round-robin into LDS.
    for (int j = wave; j < nch; j += 4) {
        const int c = cLo + j;
        float s = 0.0f;
        if (c >= 0 && c < CHUNKS) {
            const f32x4* p = reinterpret_cast<const f32x4*>(yrow + (size_t)c * HOP);
            f32x4 a = __builtin_nontemporal_load(p + lane);
            f32x4 b = __builtin_nontemporal_load(p + lane + 64);
            s = a.x * a.x + a.y * a.y + a.z * a.z + a.w * a.w
              + b.x * b.x + b.y * b.y + b.z * b.z + b.w * b.w;
            #pragma unroll
            for (int off = 32; off; off >>= 1)
                s += __shfl_xor(s, off, 64);
        }
        if (lane == 0) Ssm[j] = s;
    }
    __syncthreads();

    // Phase 2: out[t] = sqrt((S[t-2]+S[t-1]+S[t]+S[t+1]) / 2048).
    // Chunk t-2 sits at LDS index (t - t0).
    const int t = t0 + threadIdx.x;
    if (threadIdx.x < TBLK && t < t1) {
        const int j = t - t0;
        float s = Ssm[j] + Ssm[j + 1] + Ssm[j + 2] + Ssm[j + 3];
        out[(size_t)row * TOUT + t] = sqrtf(s * (1.0f / (float)FRAME));
    }
}

extern "C" void kernel_launch(void* const* d_in, const int* in_sizes, int n_in,
                              void* d_out, int out_size, void* d_ws, size_t ws_size,
                              hipStream_t stream) {
    const float* y = (const float*)d_in[0];
    float* out = (float*)d_out;
    rms_fused<<<NROWS * SEGS, 256, 0, stream>>>(y, out);
}

// Round 5
// 41.783 us; speedup vs baseline: 1.0807x; 1.0807x over previous
//
#include <hip/hip_runtime.h>

// ToRMS fused: sliding RMS energy, frame=2048, hop=512, pad=1024 each side.
// y: (64, 960000) f32  ->  out: (64, 1876) f32
//
// frame sum = sum of 4 consecutive 512-sample chunk sums (2048/512 == 4).
// Each block owns TBLK=128 output frames of one row (SEGS=15, grid=960:
// R4 showed fewer/larger blocks LOSES latency hiding — keep 15 waves/CU).
//
// Per wave-iteration: FOUR chunks at once via 16-lane groups.
// lane = 16q + r: handles chunk q of the group, loads 8x float4 at
// [r + 16k] (each 16-lane group = contiguous 256 B run -> coalescing
// identical to a fully-contiguous wave load). 8 loads in flight/lane
// (vs 2 before) and the wave reduce shrinks from 6 shfl/chunk to
// 4 shfl per 4 chunks.

#define FRAME   2048
#define HOP     512
#define NROWS   64
#define NCOLS   960000
#define CHUNKS  1875          // NCOLS / HOP (chunks never cross a row)
#define TOUT    1876          // (NCOLS + 2*1024 - FRAME)/HOP + 1
#define TBLK    128           // output frames per block
#define SEGS    15            // ceil(TOUT / TBLK)
#define CMAX    (TBLK + 3)    // max chunks a block needs

typedef float f32x4 __attribute__((ext_vector_type(4)));  // native vec type for NT loads

__global__ __launch_bounds__(256) void rms_fused(const float* __restrict__ y,
                                                 float* __restrict__ out) {
    __shared__ float Ssm[CMAX];

    const int row = blockIdx.x / SEGS;
    const int seg = blockIdx.x - row * SEGS;
    const int t0  = seg * TBLK;
    const int t1  = (t0 + TBLK < TOUT) ? (t0 + TBLK) : TOUT;
    const int cLo = t0 - 2;               // first chunk index needed (may be <0)
    const int nch = (t1 + 1) - cLo + 1;   // chunks [cLo, t1+1] inclusive (<=131)

    const int lane = threadIdx.x & 63;
    const int wave = threadIdx.x >> 6;    // 4 waves per block
    const int q    = lane >> 4;           // chunk-in-group 0..3
    const int r    = lane & 15;           // lane within 16-group

    const float* yrow = y + (size_t)row * NCOLS;

    // Phase 1: each wave computes 4 chunk sums per iteration into LDS.
    for (int g = wave; g * 4 < nch; g += 4) {
        const int j = g * 4 + q;          // LDS slot for this lane-group's chunk
        const int c = cLo + j;            // global chunk index
        float s = 0.0f;
        if (j < nch && c >= 0 && c < CHUNKS) {
            const f32x4* p = reinterpret_cast<const f32x4*>(yrow + (size_t)c * HOP);
            f32x4 v0 = __builtin_nontemporal_load(p + r);
            f32x4 v1 = __builtin_nontemporal_load(p + r + 16);
            f32x4 v2 = __builtin_nontemporal_load(p + r + 32);
            f32x4 v3 = __builtin_nontemporal_load(p + r + 48);
            f32x4 v4 = __builtin_nontemporal_load(p + r + 64);
            f32x4 v5 = __builtin_nontemporal_load(p + r + 80);
            f32x4 v6 = __builtin_nontemporal_load(p + r + 96);
            f32x4 v7 = __builtin_nontemporal_load(p + r + 112);
            float s0 = v0.x*v0.x + v0.y*v0.y + v0.z*v0.z + v0.w*v0.w;
            float s1 = v1.x*v1.x + v1.y*v1.y + v1.z*v1.z + v1.w*v1.w;
            float s2 = v2.x*v2.x + v2.y*v2.y + v2.z*v2.z + v2.w*v2.w;
            float s3 = v3.x*v3.x + v3.y*v3.y + v3.z*v3.z + v3.w*v3.w;
            float s4 = v4.x*v4.x + v4.y*v4.y + v4.z*v4.z + v4.w*v4.w;
            float s5 = v5.x*v5.x + v5.y*v5.y + v5.z*v5.z + v5.w*v5.w;
            float s6 = v6.x*v6.x + v6.y*v6.y + v6.z*v6.z + v6.w*v6.w;
            float s7 = v7.x*v7.x + v7.y*v7.y + v7.z*v7.z + v7.w*v7.w;
            s = ((s0 + s1) + (s2 + s3)) + ((s4 + s5) + (s6 + s7));
        }
        // 16-lane butterfly (reduction axis is within each 16-lane group)
        s += __shfl_xor(s, 1, 64);
        s += __shfl_xor(s, 2, 64);
        s += __shfl_xor(s, 4, 64);
        s += __shfl_xor(s, 8, 64);
        const int j2 = g * 4 + q;
        if (r == 0 && j2 < nch) Ssm[j2] = s;
    }
    __syncthreads();

    // Phase 2: out[t] = sqrt((S[t-2]+S[t-1]+S[t]+S[t+1]) / 2048).
    // Chunk t-2 sits at LDS index (t - t0).
    const int t = t0 + threadIdx.x;
    if (threadIdx.x < TBLK && t < t1) {
        const int j = t - t0;
        float s = Ssm[j] + Ssm[j + 1] + Ssm[j + 2] + Ssm[j + 3];
        out[(size_t)row * TOUT + t] = sqrtf(s * (1.0f / (float)FRAME));
    }
}

extern "C" void kernel_launch(void* const* d_in, const int* in_sizes, int n_in,
                              void* d_out, int out_size, void* d_ws, size_t ws_size,
                              hipStream_t stream) {
    const float* y = (const float*)d_in[0];
    float* out = (float*)d_out;
    rms_fused<<<NROWS * SEGS, 256, 0, stream>>>(y, out);
}